// Round 11
// baseline (195.610 us; speedup 1.0000x reference)
//
#include <hip/hip_runtime.h>

typedef __attribute__((ext_vector_type(8))) __bf16 bf16x8;
typedef __attribute__((ext_vector_type(8))) unsigned short ushort8;
typedef __attribute__((ext_vector_type(4))) unsigned short ushort4_t;
typedef __attribute__((ext_vector_type(4))) float f32x4;
typedef unsigned short ushort_t;

#define MFMA_BF16(A,B,C) __builtin_amdgcn_mfma_f32_16x16x32_bf16(A,B,C,0,0,0)

#define T_SEQ 4096
#define DM 512
#define HD_ 64
#define NH_ 8

#define LOG2E 1.4426950408889634f
#define QSCALE (0.125f * LOG2E)
#define MT4 ((size_t)4194304)          // elements of one full O = 2*T_SEQ*DM

__device__ __forceinline__ unsigned short f2b(float f){
    unsigned int u = __builtin_bit_cast(unsigned int, f);
    u += 0x7FFFu + ((u >> 16) & 1u);   // round-to-nearest-even
    return (unsigned short)(u >> 16);
}

__device__ __forceinline__ float b2f(unsigned short u){
    unsigned int x = ((unsigned int)u) << 16;
    return __builtin_bit_cast(float, x);
}

__device__ __forceinline__ float exp2_fast(float x){
#if __has_builtin(__builtin_amdgcn_exp2f)
    return __builtin_amdgcn_exp2f(x);
#else
    float r; asm("v_exp_f32 %0, %1" : "=v"(r) : "v"(x)); return r;
#endif
}

__device__ __forceinline__ float max3f(float a, float b, float c){
    return fmaxf(fmaxf(a, b), c);      // clang fuses to v_max3_f32
}

__device__ __forceinline__ unsigned cvt_pk_bf16(float a, float b){
    unsigned r;
    asm("v_cvt_pk_bf16_f32 %0, %1, %2" : "=v"(r) : "v"(a), "v"(b));
    return r;
}

__device__ __forceinline__ void gload_lds16(const void* g, void* l){
    __builtin_amdgcn_global_load_lds((const __attribute__((address_space(1))) void*)g,
                                     (__attribute__((address_space(3))) void*)l, 16, 0, 0);
}

// ---------------- GEMM: C[M,512] = (A[M,512] @ W[512,512]^T + bias) * scale ----------------
// MODE 0: f32 row-major C. MODE 1: bf16 row-major C. MODE 2: bf16 V^T write.
template<int MODE>
__device__ __forceinline__ void gemm_body(const float* __restrict__ A, const float* __restrict__ W,
                                          const float* __restrict__ bias, void* __restrict__ Cout,
                                          int m0, int n0, float scale)
{
    constexpr int K = 512, N = 512;
    __shared__ ushort_t As[128*64];
    __shared__ ushort_t Bs[128*64];

    const int tid  = threadIdx.x;
    const int lane = tid & 63;
    const int w    = tid >> 6;
    const int g    = lane >> 4;
    const int c16  = lane & 15;
    const int wm   = w >> 1, wn = w & 1;

    f32x4 acc[4][4];
#pragma unroll
    for (int i=0;i<4;i++)
#pragma unroll
        for (int j=0;j<4;j++) acc[i][j] = (f32x4){0.f,0.f,0.f,0.f};

#pragma unroll 1
    for (int kt=0; kt<K/64; kt++){
        __syncthreads();
#pragma unroll
        for (int j=0;j<4;j++){
            int cid = j*256 + tid;
            int row = cid >> 3, ch = cid & 7;
            const float* srcA = A + (size_t)(m0+row)*K + kt*64 + ch*8;
            const float* srcB = W + (size_t)(n0+row)*K + kt*64 + ch*8;
            float4 a0 = *(const float4*)srcA;
            float4 a1 = *(const float4*)(srcA+4);
            float4 b0 = *(const float4*)srcB;
            float4 b1 = *(const float4*)(srcB+4);
            ushort8 va, vb;
            va[0]=f2b(a0.x); va[1]=f2b(a0.y); va[2]=f2b(a0.z); va[3]=f2b(a0.w);
            va[4]=f2b(a1.x); va[5]=f2b(a1.y); va[6]=f2b(a1.z); va[7]=f2b(a1.w);
            vb[0]=f2b(b0.x); vb[1]=f2b(b0.y); vb[2]=f2b(b0.z); vb[3]=f2b(b0.w);
            vb[4]=f2b(b1.x); vb[5]=f2b(b1.y); vb[6]=f2b(b1.z); vb[7]=f2b(b1.w);
            int dst = row*64 + ((ch ^ (row & 7))<<3);
            *(ushort8*)&As[dst] = va;
            *(ushort8*)&Bs[dst] = vb;
        }
        __syncthreads();
#pragma unroll
        for (int ks=0; ks<2; ks++){
            bf16x8 af[4], bfr[4];
#pragma unroll
            for (int f=0; f<4; f++){
                int rowa = wm*64 + f*16 + c16;
                af[f]  = *(const bf16x8*)&As[rowa*64 + (((ks*4+g) ^ (rowa&7))<<3)];
                int rowb = wn*64 + f*16 + c16;
                bfr[f] = *(const bf16x8*)&Bs[rowb*64 + (((ks*4+g) ^ (rowb&7))<<3)];
            }
#pragma unroll
            for (int fm=0; fm<4; fm++)
#pragma unroll
                for (int fn=0; fn<4; fn++)
                    acc[fm][fn] = MFMA_BF16(af[fm], bfr[fn], acc[fm][fn]);
        }
    }
#pragma unroll
    for (int fm=0; fm<4; fm++)
#pragma unroll
        for (int fn=0; fn<4; fn++){
            int col = n0 + wn*64 + fn*16 + c16;
            float bv = bias[col];
            if (MODE == 2){
                // transposed V^T store: 4 consecutive t at fixed d -> 8B store
                int t0r = m0 + wm*64 + fm*16 + g*4;          // 4-aligned
                int b2  = t0r >> 12;                          // tile never crosses b
                int t   = t0r & 4095;
                int h2  = col >> 6, d = col & 63;
                ushort4_t u;
#pragma unroll
                for (int r=0; r<4; r++) u[r] = f2b(acc[fm][fn][r] + bv);
                ushort_t* dst = (ushort_t*)Cout + ((size_t)(b2*NH_ + h2)*HD_ + d)*T_SEQ + t;
                *(ushort4_t*)dst = u;
            } else {
#pragma unroll
                for (int r=0; r<4; r++){
                    int rowm = m0 + wm*64 + fm*16 + g*4 + r;
                    float vv = (acc[fm][fn][r] + bv) * scale;
                    if (MODE == 1) ((ushort_t*)Cout)[(size_t)rowm*N + col] = f2b(vv);
                    else           ((float*)Cout)[(size_t)rowm*N + col]   = vv;
                }
            }
        }
}

__global__ __launch_bounds__(256,2) void gemm_qkv_kernel(
    const float* __restrict__ q, const float* __restrict__ k, const float* __restrict__ v,
    const float* __restrict__ Wq, const float* __restrict__ bq,
    const float* __restrict__ Wk, const float* __restrict__ bk,
    const float* __restrict__ Wv, const float* __restrict__ bv,
    ushort_t* __restrict__ QKVp)
{
    int z = blockIdx.z;
    const float* A  = (z==0) ? q  : (z==1 ? k  : v);
    const float* W  = (z==0) ? Wq : (z==1 ? Wk : Wv);
    const float* bb = (z==0) ? bq : (z==1 ? bk : bv);
    ushort_t* C = QKVp + (size_t)z * MT4;
    if (z == 2)
        gemm_body<2>(A, W, bb, C, blockIdx.x*128, blockIdx.y*128, 1.0f);   // V^T direct
    else
        gemm_body<1>(A, W, bb, C, blockIdx.x*128, blockIdx.y*128,
                     (z==0) ? QSCALE : 1.0f);                              // bake 0.125*log2e into Q
}

__global__ __launch_bounds__(256,2) void gemm_out_kernel(
    const float* __restrict__ O, const float* __restrict__ Wo,
    const float* __restrict__ bo, float* __restrict__ out)
{
    gemm_body<0>(O, Wo, bo, out, blockIdx.x*128, blockIdx.y*128, 1.0f);
}

// ---------------- Flash attention (r9 layouts EXACTLY, kv-split-3) ----------------
// 512 thr (8 waves), 128 q rows/block (wave = 16 rows), KV tile 64, dbuf K/V^T.
// Swapped QK^T: S^T = mfma(K, Q): lane owns q-row c16, kv = n*16+g*4+r.
// One-tile-delayed PV; ones-MFMA lsum. Each block covers kv SEGMENT seg:
// tiles [seg*21, seg*21+21) (seg 2: 22 tiles). Stores UNNORMALIZED bf16 partial
// + per-row (m2, asum). Grid 1536 = exactly 2 rounds of 768 blocks at 3/CU.
__global__ __launch_bounds__(512,4) void flash_kernel(
    const ushort_t* __restrict__ Qp, const ushort_t* __restrict__ Kp, const ushort_t* __restrict__ Vt,
    const float* __restrict__ frac, const float* __restrict__ alphap, const float* __restrict__ alphan,
    ushort_t* __restrict__ Op01, ushort_t* __restrict__ Op2, float2* __restrict__ ml)
{
    // XCD-aware: 2 bh per XCD (6 (bh,seg) streams); K/V^T for 2 bh ~ 4 MB in L2
    int i    = blockIdx.x;
    int xcd  = i & 7;
    int j    = i >> 3;                   // [0,192)
    int strm = xcd*6 + (j>>5);           // [0,48)
    int qt   = j & 31;
    int bh   = strm / 3;
    int seg  = strm - bh*3;              // [0,3)
    int b    = bh >> 3, h = bh & 7;
    int q0   = qt * 128;
    const int kt0 = seg*21;
    const int nt  = (seg==2) ? 22 : 21;

    const int tid  = threadIdx.x;
    const int w    = tid >> 6;           // [0,8)
    const int lane = tid & 63;
    const int g    = lane >> 4;
    const int c16  = lane & 15;

    __shared__ ushort_t Ks [2][64*64];   // [kv][d], chunk ^ (row&7)
    __shared__ ushort_t VTs[2][64*64];   // [d][kv], chunk ^ (row&7)
    __shared__ ushort_t PW [8][16*64];   // per-wave P^T as [q][kv], pair-swizzled

    const ushort_t* Qbase = Qp + (size_t)(b*T_SEQ)*DM + h*HD_;
    const ushort_t* Kbase = Kp + (size_t)(b*T_SEQ)*DM + h*HD_;
    const ushort_t* Vtb   = Vt + (size_t)bh*HD_*T_SEQ;
    const float*    fr    = frac + b*T_SEQ;
    const float c1 = 0.5f*(alphap[h] + alphan[h]) * LOG2E;   // bias = c1*dd + c2*|dd|
    const float c2 = 0.5f*(alphap[h] - alphan[h]) * LOG2E;
    const int qrow = q0 + w*16;

    // Q fragments (B-operand: col = c16, k = ks*32 + g*8 + e)
    bf16x8 qa[2];
#pragma unroll
    for (int ks=0; ks<2; ks++)
        qa[ks] = *(const bf16x8*)(Qbase + (size_t)(qrow + c16)*DM + ks*32 + g*8);
    const float fi = fr[qrow + c16];     // this lane's q-row frac

    // ones vector for the lsum MFMA
    ushort8 ou;
#pragma unroll
    for (int jj=0;jj<8;jj++) ou[jj] = 0x3F80;
    const bf16x8 ones = __builtin_bit_cast(bf16x8, ou);

    float m2 = -1e30f;                   // running max (log2 domain)
    f32x4 acc[4];                        // O^T: lane holds q=c16, d = dt*16+g*4+r
    f32x4 asum;                          // row-sum accumulator (all regs equal)
#pragma unroll
    for (int dt=0; dt<4; dt++) acc[dt] = (f32x4){0.f,0.f,0.f,0.f};
    asum = (f32x4){0.f,0.f,0.f,0.f};

    bf16x8 vbp[2][4];                    // V^T frags of tile t, consumed by PV at t+1

#define STAGE(BUF, KV0)                                                          \
    {                                                                            \
        int cb  = w*64;                                                          \
        int idx = cb + lane;                                                     \
        int row = idx >> 3, cc = idx & 7;                                        \
        int cs  = cc ^ (row & 7);                                                \
        gload_lds16(Kbase + (size_t)((KV0)+row)*DM + cs*8, &Ks[BUF][cb*8]);      \
        gload_lds16(Vtb + (size_t)row*T_SEQ + (KV0) + cs*8, &VTs[BUF][cb*8]);    \
    }

    STAGE(0, kt0*64);
    asm volatile("s_waitcnt vmcnt(0)" ::: "memory");
    __syncthreads();

    int buf = 0;
#pragma unroll 1
    for (int kt=kt0; kt<kt0+nt; kt++){
        int kv0 = kt*64;
        if (kt+1 < kt0+nt) STAGE(buf^1, kv0+64);

        // --- P(t-1) fragment reads (issue early; consumed by PV cluster) ---
        bf16x8 pb0, pb1;
        if (kt > kt0){
            pb0 = *(const bf16x8*)&PW[w][c16*64 + (((    g) ^ (c16&7))<<3)];
            pb1 = *(const bf16x8*)&PW[w][c16*64 + (((4 + g) ^ (c16&7))<<3)];
        }

        // --- S^T = K Q^T (Q pre-scaled by 0.125*log2e) ---
        f32x4 s[4];                      // s[n][r]: kv = n*16+g*4+r, q = c16
#pragma unroll
        for (int n=0; n<4; n++) s[n] = (f32x4){0.f,0.f,0.f,0.f};
        __builtin_amdgcn_s_setprio(1);
#pragma unroll
        for (int n=0; n<4; n++){
#pragma unroll
            for (int ks=0; ks<2; ks++){
                int row = n*16 + c16;
                bf16x8 kb = *(const bf16x8*)&Ks[buf][row*64 + (((ks*4+g) ^ (row&7))<<3)];
                s[n] = MFMA_BF16(kb, qa[ks], s[n]);   // A=K, B=Q
            }
        }
        // --- PV(t-1) + lsum(t-1): all operands in registers ---
        if (kt > kt0){
            asum = MFMA_BF16(ones, pb0, asum);
#pragma unroll
            for (int dt=0; dt<4; dt++) acc[dt] = MFMA_BF16(vbp[0][dt], pb0, acc[dt]);
            asum = MFMA_BF16(ones, pb1, asum);
#pragma unroll
            for (int dt=0; dt<4; dt++) acc[dt] = MFMA_BF16(vbp[1][dt], pb1, acc[dt]);
        }
        __builtin_amdgcn_s_setprio(0);
        // pin compile-time order: PW pack-writes below must not move above pb reads
        __builtin_amdgcn_sched_barrier(0);

        // --- bias (log2 domain, select-free algebra) ---
#pragma unroll
        for (int n=0; n<4; n++){
            f32x4 fj = *(const f32x4*)&fr[kv0 + n*16 + g*4];
#pragma unroll
            for (int r=0; r<4; r++){
                float dd = fj[r] - fi;
                s[n][r] = fmaf(c1, dd, fmaf(c2, fabsf(dd), s[n][r]));
            }
        }
        // in-lane max via max3 trees, then cross-lane (4 lanes share a q-row)
        float mx;
        {
            float t0 = max3f(s[0][0], s[0][1], s[0][2]);
            float t1 = max3f(s[0][3], s[1][0], s[1][1]);
            float t2 = max3f(s[1][2], s[1][3], s[2][0]);
            float t3 = max3f(s[2][1], s[2][2], s[2][3]);
            float t4 = max3f(s[3][0], s[3][1], s[3][2]);
            mx = fmaxf(max3f(t0, t1, t2), max3f(t3, t4, s[3][3]));
        }
        mx = fmaxf(mx, __shfl_xor(mx, 16));
        mx = fmaxf(mx, __shfl_xor(mx, 32));

        // --- defer-max rescale (threshold 12 in log2 ~ e^8.3) ---
        if (__any(mx > m2 + 12.0f)){
            float mnew = fmaxf(m2, mx);
            float fac  = exp2_fast(m2 - mnew);
#pragma unroll
            for (int r=0; r<4; r++) asum[r] *= fac;
#pragma unroll
            for (int dt=0; dt<4; dt++)
#pragma unroll
                for (int r=0; r<4; r++) acc[dt][r] *= fac;
            m2 = mnew;
        }

        // --- exp2, pack P -> LDS ---
#pragma unroll
        for (int n=0; n<4; n++){
#pragma unroll
            for (int r=0; r<4; r++) s[n][r] = exp2_fast(s[n][r] - m2);
            unsigned pk0 = cvt_pk_bf16(s[n][0], s[n][1]);
            unsigned pk1 = cvt_pk_bf16(s[n][2], s[n][3]);
            uint2 u; u.x = pk0; u.y = pk1;
            int off = c16*64 + (((n*2 + (g>>1)) ^ (c16 & 7))<<3) + ((g&1)<<2);
            *(uint2*)&PW[w][off] = u;
        }

        // --- V(t) -> regs for next iteration's PV (VTs[buf] stable this iter) ---
#pragma unroll
        for (int ks=0; ks<2; ks++)
#pragma unroll
            for (int dt=0; dt<4; dt++){
                int vr = dt*16 + c16;
                vbp[ks][dt] = *(const bf16x8*)&VTs[buf][vr*64 + (((ks*4+g) ^ (vr&7))<<3)];
            }

        asm volatile("s_waitcnt vmcnt(0)" ::: "memory");
        __syncthreads();
        buf ^= 1;
    }
#undef STAGE

    // --- epilogue PV(last): PW visible (final barrier crossed) ---
    {
        bf16x8 pb0 = *(const bf16x8*)&PW[w][c16*64 + (((    g) ^ (c16&7))<<3)];
        bf16x8 pb1 = *(const bf16x8*)&PW[w][c16*64 + (((4 + g) ^ (c16&7))<<3)];
        asum = MFMA_BF16(ones, pb0, asum);
#pragma unroll
        for (int dt=0; dt<4; dt++) acc[dt] = MFMA_BF16(vbp[0][dt], pb0, acc[dt]);
        asum = MFMA_BF16(ones, pb1, asum);
#pragma unroll
        for (int dt=0; dt<4; dt++) acc[dt] = MFMA_BF16(vbp[1][dt], pb1, acc[dt]);
    }

    // --- store UNNORMALIZED bf16 partial + (m2, asum) ---
    ushort_t* obase = (seg < 2) ? (Op01 + (size_t)seg*MT4) : Op2;
    ushort_t* orow  = obase + (size_t)(b*T_SEQ + qrow + c16)*DM + h*HD_;
#pragma unroll
    for (int dt=0; dt<4; dt++){
        ushort4_t u;
#pragma unroll
        for (int r=0; r<4; r++) u[r] = f2b(acc[dt][r]);
        *(ushort4_t*)(orow + dt*16 + g*4) = u;
    }
    if (g == 0){
        float2 v2; v2.x = m2; v2.y = asum[0];
        ml[(size_t)(seg*16 + bh)*T_SEQ + (qrow + c16)] = v2;
    }
}

// ---------------- merge3: O = sum_s A_s*w_s / sum_s l_s*w_s  (f32 out) ----------------
__global__ __launch_bounds__(256) void merge3_kernel(const ushort_t* __restrict__ Op01,
                                                     const ushort_t* __restrict__ Op2,
                                                     const float2* __restrict__ ml,
                                                     float* __restrict__ Obf)
{
    int idx = blockIdx.x*256 + threadIdx.x;      // [0, 524288)
    int d8  = idx & 7;
    int h   = (idx >> 3) & 7;
    int row = idx >> 6;                           // [0, 8192)
    int b   = row >> 12, t = row & 4095;
    int bh  = b*NH_ + h;

    float2 p0 = ml[(size_t)bh*T_SEQ + t];
    float2 p1 = ml[(size_t)(16 + bh)*T_SEQ + t];
    float2 p2 = ml[(size_t)(32 + bh)*T_SEQ + t];
    float M  = max3f(p0.x, p1.x, p2.x);
    float w0 = exp2_fast(p0.x - M);
    float w1 = exp2_fast(p1.x - M);
    float w2 = exp2_fast(p2.x - M);
    float inv = 1.0f / (p0.y*w0 + p1.y*w1 + p2.y*w2);
    float s0 = w0*inv, s1 = w1*inv, s2 = w2*inv;

    size_t off = (size_t)row*DM + h*HD_ + d8*8;
    ushort8 a0 = *(const ushort8*)(Op01 + off);
    ushort8 a1 = *(const ushort8*)(Op01 + MT4 + off);
    ushort8 a2 = *(const ushort8*)(Op2 + off);
    float o[8];
#pragma unroll
    for (int r=0; r<8; r++)
        o[r] = b2f(a0[r])*s0 + b2f(a1[r])*s1 + b2f(a2[r])*s2;
    float4 o0; o0.x=o[0]; o0.y=o[1]; o0.z=o[2]; o0.w=o[3];
    float4 o1; o1.x=o[4]; o1.y=o[5]; o1.z=o[6]; o1.w=o[7];
    *(float4*)(Obf + off)     = o0;
    *(float4*)(Obf + off + 4) = o1;
}

// ---------------- launcher ----------------
extern "C" void kernel_launch(void* const* d_in, const int* in_sizes, int n_in,
                              void* d_out, int out_size, void* d_ws, size_t ws_size,
                              hipStream_t stream)
{
    const float* q  = (const float*)d_in[0];
    const float* k  = (const float*)d_in[1];
    const float* v  = (const float*)d_in[2];
    const float* fr = (const float*)d_in[3];
    const float* Wq = (const float*)d_in[4];
    const float* bq = (const float*)d_in[5];
    const float* Wk = (const float*)d_in[6];
    const float* bk = (const float*)d_in[7];
    const float* Wv = (const float*)d_in[8];
    const float* bv = (const float*)d_in[9];
    const float* Wo = (const float*)d_in[10];
    const float* bo = (const float*)d_in[11];
    const float* ap = (const float*)d_in[12];
    const float* an = (const float*)d_in[13];

    ushort_t* QKVp = (ushort_t*)d_ws;                 // Q, K, V^T bf16 (24 MB)
    ushort_t* Op2  = QKVp + 3*MT4;                    // seg-2 partial bf16 (8 MB)
    float2*   mlb  = (float2*)(QKVp + 4*MT4);         // (m, lsum) x 48 rows (1.5 MB)
    ushort_t* Op01 = (ushort_t*)d_out;                // seg-0/1 partials in d_out (16 MB, dead until gemm_out)
    float*    Obf  = (float*)d_ws;                    // merged f32 O over dead Q+K regions (16 MB)

    dim3 gq(64, 4, 3);
    gemm_qkv_kernel<<<gq, 256, 0, stream>>>(q,k,v,Wq,bq,Wk,bk,Wv,bv,QKVp);

    flash_kernel<<<1536, 512, 0, stream>>>(QKVp, QKVp + MT4, QKVp + 2*MT4, fr, ap, an,
                                           Op01, Op2, mlb);

    merge3_kernel<<<2048, 256, 0, stream>>>(Op01, Op2, mlb, Obf);

    dim3 go(64, 4, 1);
    gemm_out_kernel<<<go, 256, 0, stream>>>(Obf, Wo, bo, (float*)d_out);
}

// Round 14
// 167.156 us; speedup vs baseline: 1.1702x; 1.1702x over previous
//
#include <hip/hip_runtime.h>

typedef __attribute__((ext_vector_type(8))) __bf16 bf16x8;
typedef __attribute__((ext_vector_type(8))) unsigned short ushort8;
typedef __attribute__((ext_vector_type(4))) unsigned short ushort4_t;
typedef __attribute__((ext_vector_type(4))) float f32x4;
typedef unsigned short ushort_t;

#define MFMA_BF16(A,B,C) __builtin_amdgcn_mfma_f32_16x16x32_bf16(A,B,C,0,0,0)

#define T_SEQ 4096
#define DM 512
#define HD_ 64
#define NH_ 8

#define LOG2E 1.4426950408889634f
#define QSCALE (0.125f * LOG2E)

__device__ __forceinline__ unsigned short f2b(float f){
    unsigned int u = __builtin_bit_cast(unsigned int, f);
    u += 0x7FFFu + ((u >> 16) & 1u);   // round-to-nearest-even
    return (unsigned short)(u >> 16);
}

__device__ __forceinline__ float exp2_fast(float x){
#if __has_builtin(__builtin_amdgcn_exp2f)
    return __builtin_amdgcn_exp2f(x);
#else
    float r; asm("v_exp_f32 %0, %1" : "=v"(r) : "v"(x)); return r;
#endif
}

__device__ __forceinline__ float max3f(float a, float b, float c){
    return fmaxf(fmaxf(a, b), c);      // clang fuses to v_max3_f32
}

__device__ __forceinline__ unsigned cvt_pk_bf16(float a, float b){
    unsigned r;
    asm("v_cvt_pk_bf16_f32 %0, %1, %2" : "=v"(r) : "v"(a), "v"(b));
    return r;
}

__device__ __forceinline__ void gload_lds16(const void* g, void* l){
    __builtin_amdgcn_global_load_lds((const __attribute__((address_space(1))) void*)g,
                                     (__attribute__((address_space(3))) void*)l, 16, 0, 0);
}

// ---------------- GEMM: C[M,512] = (A[M,512] @ W[512,512]^T + bias) * scale ----------------
// MODE 0: f32 row-major C. MODE 1: bf16 row-major C. MODE 2: bf16 V^T write:
//   Vt[(b*8+h)*64 + d][t] <- C[bt][col], b=bt>>12, t=bt&4095, h=col>>6, d=col&63.
template<int MODE>
__device__ __forceinline__ void gemm_body(const float* __restrict__ A, const float* __restrict__ W,
                                          const float* __restrict__ bias, void* __restrict__ Cout,
                                          int m0, int n0, float scale)
{
    constexpr int K = 512, N = 512;
    __shared__ ushort_t As[128*64];
    __shared__ ushort_t Bs[128*64];

    const int tid  = threadIdx.x;
    const int lane = tid & 63;
    const int w    = tid >> 6;
    const int g    = lane >> 4;
    const int c16  = lane & 15;
    const int wm   = w >> 1, wn = w & 1;

    f32x4 acc[4][4];
#pragma unroll
    for (int i=0;i<4;i++)
#pragma unroll
        for (int j=0;j<4;j++) acc[i][j] = (f32x4){0.f,0.f,0.f,0.f};

#pragma unroll 1
    for (int kt=0; kt<K/64; kt++){
        __syncthreads();
#pragma unroll
        for (int j=0;j<4;j++){
            int cid = j*256 + tid;
            int row = cid >> 3, ch = cid & 7;
            const float* srcA = A + (size_t)(m0+row)*K + kt*64 + ch*8;
            const float* srcB = W + (size_t)(n0+row)*K + kt*64 + ch*8;
            float4 a0 = *(const float4*)srcA;
            float4 a1 = *(const float4*)(srcA+4);
            float4 b0 = *(const float4*)srcB;
            float4 b1 = *(const float4*)(srcB+4);
            ushort8 va, vb;
            va[0]=f2b(a0.x); va[1]=f2b(a0.y); va[2]=f2b(a0.z); va[3]=f2b(a0.w);
            va[4]=f2b(a1.x); va[5]=f2b(a1.y); va[6]=f2b(a1.z); va[7]=f2b(a1.w);
            vb[0]=f2b(b0.x); vb[1]=f2b(b0.y); vb[2]=f2b(b0.z); vb[3]=f2b(b0.w);
            vb[4]=f2b(b1.x); vb[5]=f2b(b1.y); vb[6]=f2b(b1.z); vb[7]=f2b(b1.w);
            int dst = row*64 + ((ch ^ (row & 7))<<3);
            *(ushort8*)&As[dst] = va;
            *(ushort8*)&Bs[dst] = vb;
        }
        __syncthreads();
#pragma unroll
        for (int ks=0; ks<2; ks++){
            bf16x8 af[4], bfr[4];
#pragma unroll
            for (int f=0; f<4; f++){
                int rowa = wm*64 + f*16 + c16;
                af[f]  = *(const bf16x8*)&As[rowa*64 + (((ks*4+g) ^ (rowa&7))<<3)];
                int rowb = wn*64 + f*16 + c16;
                bfr[f] = *(const bf16x8*)&Bs[rowb*64 + (((ks*4+g) ^ (rowb&7))<<3)];
            }
#pragma unroll
            for (int fm=0; fm<4; fm++)
#pragma unroll
                for (int fn=0; fn<4; fn++)
                    acc[fm][fn] = MFMA_BF16(af[fm], bfr[fn], acc[fm][fn]);
        }
    }
#pragma unroll
    for (int fm=0; fm<4; fm++)
#pragma unroll
        for (int fn=0; fn<4; fn++){
            int col = n0 + wn*64 + fn*16 + c16;
            float bv = bias[col];
            if (MODE == 2){
                // transposed V^T store: 4 consecutive t at fixed d -> 8B store
                int t0r = m0 + wm*64 + fm*16 + g*4;          // 4-aligned
                int b2  = t0r >> 12;                          // tile never crosses b
                int t   = t0r & 4095;
                int h2  = col >> 6, d = col & 63;
                ushort4_t u;
#pragma unroll
                for (int r=0; r<4; r++) u[r] = f2b(acc[fm][fn][r] + bv);
                ushort_t* dst = (ushort_t*)Cout + ((size_t)(b2*NH_ + h2)*HD_ + d)*T_SEQ + t;
                *(ushort4_t*)dst = u;
            } else {
#pragma unroll
                for (int r=0; r<4; r++){
                    int rowm = m0 + wm*64 + fm*16 + g*4 + r;
                    float vv = (acc[fm][fn][r] + bv) * scale;
                    if (MODE == 1) ((ushort_t*)Cout)[(size_t)rowm*N + col] = f2b(vv);
                    else           ((float*)Cout)[(size_t)rowm*N + col]   = vv;
                }
            }
        }
}

__global__ __launch_bounds__(256,2) void gemm_qkv_kernel(
    const float* __restrict__ q, const float* __restrict__ k, const float* __restrict__ v,
    const float* __restrict__ Wq, const float* __restrict__ bq,
    const float* __restrict__ Wk, const float* __restrict__ bk,
    const float* __restrict__ Wv, const float* __restrict__ bv,
    ushort_t* __restrict__ QKVp)
{
    int z = blockIdx.z;
    const float* A  = (z==0) ? q  : (z==1 ? k  : v);
    const float* W  = (z==0) ? Wq : (z==1 ? Wk : Wv);
    const float* bb = (z==0) ? bq : (z==1 ? bk : bv);
    ushort_t* C = QKVp + (size_t)z * (size_t)(2*T_SEQ) * DM;
    if (z == 2)
        gemm_body<2>(A, W, bb, C, blockIdx.x*128, blockIdx.y*128, 1.0f);   // V^T direct
    else
        gemm_body<1>(A, W, bb, C, blockIdx.x*128, blockIdx.y*128,
                     (z==0) ? QSCALE : 1.0f);                               // bake 0.125*log2e into Q
}

__global__ __launch_bounds__(256,2) void gemm_out_kernel(
    const float* __restrict__ O, const float* __restrict__ Wo,
    const float* __restrict__ bo, float* __restrict__ out)
{
    gemm_body<0>(O, Wo, bo, out, blockIdx.x*128, blockIdx.y*128, 1.0f);
}

// ---------------- Flash attention (r8 pipeline + ones-MFMA lsum) ----------------
// 512 thr (8 waves), 128 q rows/block (wave = 16 rows), KV tile 64, dbuf K/V^T.
// Swapped QK^T: S^T = mfma(K, Q): lane owns q-row c16, kv = n*16+g*4+r.
// One-tile-delayed PV; lsum = ones-MFMA column-sums of the SAME pb that PV uses
// (denominator == sum of numerator weights; cannot diverge from PV).
__global__ __launch_bounds__(512,4) void flash_kernel(
    const ushort_t* __restrict__ Qp, const ushort_t* __restrict__ Kp, const ushort_t* __restrict__ Vt,
    const float* __restrict__ frac, const float* __restrict__ alphap, const float* __restrict__ alphan,
    float* __restrict__ O)
{
    // XCD-aware: 2 bh per XCD slot; their K/V (2 MB) live in that XCD's L2
    int i    = blockIdx.x;
    int slot = i & 7;
    int seq  = i >> 3;                   // [0,64)
    int bh   = slot*2 + (seq >> 5);
    int qt   = seq & 31;
    int b    = bh >> 3, h = bh & 7;
    int q0   = qt * 128;

    const int tid  = threadIdx.x;
    const int w    = tid >> 6;           // [0,8)
    const int lane = tid & 63;
    const int g    = lane >> 4;
    const int c16  = lane & 15;

    __shared__ ushort_t Ks [2][64*64];   // [kv][d], chunk ^ (row&7)
    __shared__ ushort_t VTs[2][64*64];   // [d][kv], chunk ^ (row&7)
    __shared__ ushort_t PW [8][16*64];   // per-wave P^T as [q][kv], pair-swizzled

    const ushort_t* Qbase = Qp + (size_t)(b*T_SEQ)*DM + h*HD_;
    const ushort_t* Kbase = Kp + (size_t)(b*T_SEQ)*DM + h*HD_;
    const ushort_t* Vtb   = Vt + (size_t)bh*HD_*T_SEQ;
    const float*    fr    = frac + b*T_SEQ;
    const float c1 = 0.5f*(alphap[h] + alphan[h]) * LOG2E;   // bias = c1*dd + c2*|dd|
    const float c2 = 0.5f*(alphap[h] - alphan[h]) * LOG2E;
    const int qrow = q0 + w*16;

    // Q fragments (B-operand: col = c16, k = ks*32 + g*8 + e)
    bf16x8 qa[2];
#pragma unroll
    for (int ks=0; ks<2; ks++)
        qa[ks] = *(const bf16x8*)(Qbase + (size_t)(qrow + c16)*DM + ks*32 + g*8);
    const float fi = fr[qrow + c16];     // this lane's q-row frac

    // ones vector for the lsum MFMA
    ushort8 ou;
#pragma unroll
    for (int j=0;j<8;j++) ou[j] = 0x3F80;
    const bf16x8 ones = __builtin_bit_cast(bf16x8, ou);

    float m2 = -1e30f;                   // running max (log2 domain)
    f32x4 acc[4];                        // O^T: lane holds q=c16, d = dt*16+g*4+r
    f32x4 asum;                          // row-sum accumulator (all regs equal)
#pragma unroll
    for (int dt=0; dt<4; dt++) acc[dt] = (f32x4){0.f,0.f,0.f,0.f};
    asum = (f32x4){0.f,0.f,0.f,0.f};

    bf16x8 vbp[2][4];                    // V^T frags of tile t, consumed by PV at t+1

#define STAGE(BUF, KV0)                                                          \
    {                                                                            \
        int cb  = w*64;                                                          \
        int idx = cb + lane;                                                     \
        int row = idx >> 3, cc = idx & 7;                                        \
        int cs  = cc ^ (row & 7);                                                \
        gload_lds16(Kbase + (size_t)((KV0)+row)*DM + cs*8, &Ks[BUF][cb*8]);      \
        gload_lds16(Vtb + (size_t)row*T_SEQ + (KV0) + cs*8, &VTs[BUF][cb*8]);    \
    }

    STAGE(0, 0);
    asm volatile("s_waitcnt vmcnt(0)" ::: "memory");
    __syncthreads();

    int buf = 0;
#pragma unroll 1
    for (int kt=0; kt<T_SEQ/64; kt++){
        int kv0 = kt*64;
        if (kt+1 < T_SEQ/64) STAGE(buf^1, kv0+64);

        // --- P(t-1) fragment reads (issue early; consumed by PV cluster) ---
        bf16x8 pb0, pb1;
        if (kt > 0){
            pb0 = *(const bf16x8*)&PW[w][c16*64 + (((    g) ^ (c16&7))<<3)];
            pb1 = *(const bf16x8*)&PW[w][c16*64 + (((4 + g) ^ (c16&7))<<3)];
        }

        // --- S^T = K Q^T (Q pre-scaled by 0.125*log2e) ---
        f32x4 s[4];                      // s[n][r]: kv = n*16+g*4+r, q = c16
#pragma unroll
        for (int n=0; n<4; n++) s[n] = (f32x4){0.f,0.f,0.f,0.f};
        __builtin_amdgcn_s_setprio(1);
#pragma unroll
        for (int n=0; n<4; n++){
#pragma unroll
            for (int ks=0; ks<2; ks++){
                int row = n*16 + c16;
                bf16x8 kb = *(const bf16x8*)&Ks[buf][row*64 + (((ks*4+g) ^ (row&7))<<3)];
                s[n] = MFMA_BF16(kb, qa[ks], s[n]);   // A=K, B=Q
            }
        }
        // --- PV(t-1) + lsum(t-1): all operands in registers ---
        if (kt > 0){
            asum = MFMA_BF16(ones, pb0, asum);
#pragma unroll
            for (int dt=0; dt<4; dt++) acc[dt] = MFMA_BF16(vbp[0][dt], pb0, acc[dt]);
            asum = MFMA_BF16(ones, pb1, asum);
#pragma unroll
            for (int dt=0; dt<4; dt++) acc[dt] = MFMA_BF16(vbp[1][dt], pb1, acc[dt]);
        }
        __builtin_amdgcn_s_setprio(0);
        // pin compile-time order: PW pack-writes below must not move above pb reads
        __builtin_amdgcn_sched_barrier(0);

        // --- bias (log2 domain, select-free algebra) ---
#pragma unroll
        for (int n=0; n<4; n++){
            f32x4 fj = *(const f32x4*)&fr[kv0 + n*16 + g*4];
#pragma unroll
            for (int r=0; r<4; r++){
                float dd = fj[r] - fi;
                s[n][r] = fmaf(c1, dd, fmaf(c2, fabsf(dd), s[n][r]));
            }
        }
        // in-lane max via max3 trees, then cross-lane (4 lanes share a q-row)
        float mx;
        {
            float t0 = max3f(s[0][0], s[0][1], s[0][2]);
            float t1 = max3f(s[0][3], s[1][0], s[1][1]);
            float t2 = max3f(s[1][2], s[1][3], s[2][0]);
            float t3 = max3f(s[2][1], s[2][2], s[2][3]);
            float t4 = max3f(s[3][0], s[3][1], s[3][2]);
            mx = fmaxf(max3f(t0, t1, t2), max3f(t3, t4, s[3][3]));
        }
        mx = fmaxf(mx, __shfl_xor(mx, 16));
        mx = fmaxf(mx, __shfl_xor(mx, 32));

        // --- defer-max rescale (threshold 12 in log2 ~ e^8.3) ---
        // acc/asum already include PV(t-1) -> ordering identical to r7/r8
        if (__any(mx > m2 + 12.0f)){
            float mnew = fmaxf(m2, mx);
            float fac  = exp2_fast(m2 - mnew);
#pragma unroll
            for (int r=0; r<4; r++) asum[r] *= fac;
#pragma unroll
            for (int dt=0; dt<4; dt++)
#pragma unroll
                for (int r=0; r<4; r++) acc[dt][r] *= fac;
            m2 = mnew;
        }

        // --- exp2, pack P -> LDS ---
#pragma unroll
        for (int n=0; n<4; n++){
#pragma unroll
            for (int r=0; r<4; r++) s[n][r] = exp2_fast(s[n][r] - m2);
            unsigned pk0 = cvt_pk_bf16(s[n][0], s[n][1]);
            unsigned pk1 = cvt_pk_bf16(s[n][2], s[n][3]);
            uint2 u; u.x = pk0; u.y = pk1;
            int off = c16*64 + (((n*2 + (g>>1)) ^ (c16 & 7))<<3) + ((g&1)<<2);
            *(uint2*)&PW[w][off] = u;
        }

        // --- V(t) -> regs for next iteration's PV (VTs[buf] stable this iter) ---
#pragma unroll
        for (int ks=0; ks<2; ks++)
#pragma unroll
            for (int dt=0; dt<4; dt++){
                int vr = dt*16 + c16;
                vbp[ks][dt] = *(const bf16x8*)&VTs[buf][vr*64 + (((ks*4+g) ^ (vr&7))<<3)];
            }

        asm volatile("s_waitcnt vmcnt(0)" ::: "memory");
        __syncthreads();
        buf ^= 1;
    }
#undef STAGE

    // --- epilogue PV(T-1): PW visible (final barrier crossed) ---
    {
        bf16x8 pb0 = *(const bf16x8*)&PW[w][c16*64 + (((    g) ^ (c16&7))<<3)];
        bf16x8 pb1 = *(const bf16x8*)&PW[w][c16*64 + (((4 + g) ^ (c16&7))<<3)];
        asum = MFMA_BF16(ones, pb0, asum);
#pragma unroll
        for (int dt=0; dt<4; dt++) acc[dt] = MFMA_BF16(vbp[0][dt], pb0, acc[dt]);
        asum = MFMA_BF16(ones, pb1, asum);
#pragma unroll
        for (int dt=0; dt<4; dt++) acc[dt] = MFMA_BF16(vbp[1][dt], pb1, acc[dt]);
    }

    // --- store: O[b, qrow+c16, h*64 + dt*16 + g*4 + r] ---
    float inv = 1.0f / asum[0];
    float* orow = O + (size_t)(b*T_SEQ + qrow + c16)*DM + h*HD_;
#pragma unroll
    for (int dt=0; dt<4; dt++){
        float4 o4;
        o4.x = acc[dt][0]*inv; o4.y = acc[dt][1]*inv;
        o4.z = acc[dt][2]*inv; o4.w = acc[dt][3]*inv;
        *(float4*)(orow + dt*16 + g*4) = o4;
    }
}

// ---------------- launcher ----------------
extern "C" void kernel_launch(void* const* d_in, const int* in_sizes, int n_in,
                              void* d_out, int out_size, void* d_ws, size_t ws_size,
                              hipStream_t stream)
{
    const float* q  = (const float*)d_in[0];
    const float* k  = (const float*)d_in[1];
    const float* v  = (const float*)d_in[2];
    const float* fr = (const float*)d_in[3];
    const float* Wq = (const float*)d_in[4];
    const float* bq = (const float*)d_in[5];
    const float* Wk = (const float*)d_in[6];
    const float* bk = (const float*)d_in[7];
    const float* Wv = (const float*)d_in[8];
    const float* bv = (const float*)d_in[9];
    const float* Wo = (const float*)d_in[10];
    const float* bo = (const float*)d_in[11];
    const float* ap = (const float*)d_in[12];
    const float* an = (const float*)d_in[13];

    const size_t MT = (size_t)(2*T_SEQ) * DM;              // 4M elements
    ushort_t* QKVp = (ushort_t*)d_ws;                      // Q, K, V^T bf16 (24 MB)
    float*    O    = (float*)((char*)d_ws + 3*MT*sizeof(ushort_t)); // 16 MB f32

    dim3 gq(64, 4, 3);
    gemm_qkv_kernel<<<gq, 256, 0, stream>>>(q,k,v,Wq,bq,Wk,bk,Wv,bv,QKVp);

    flash_kernel<<<512, 512, 0, stream>>>(QKVp, QKVp + MT, QKVp + 2*MT, fr, ap, an, O);

    dim3 go(64, 4, 1);
    gemm_out_kernel<<<go, 256, 0, stream>>>(O, Wo, bo, (float*)d_out);
}

// Round 16
// 166.950 us; speedup vs baseline: 1.1717x; 1.0012x over previous
//
#include <hip/hip_runtime.h>

typedef __attribute__((ext_vector_type(8))) __bf16 bf16x8;
typedef __attribute__((ext_vector_type(8))) unsigned short ushort8;
typedef __attribute__((ext_vector_type(4))) unsigned short ushort4_t;
typedef __attribute__((ext_vector_type(4))) float f32x4;
typedef unsigned short ushort_t;

#define MFMA_BF16(A,B,C) __builtin_amdgcn_mfma_f32_16x16x32_bf16(A,B,C,0,0,0)

#define T_SEQ 4096
#define DM 512
#define HD_ 64
#define NH_ 8

#define LOG2E 1.4426950408889634f
#define QSCALE (0.125f * LOG2E)

__device__ __forceinline__ unsigned short f2b(float f){
    unsigned int u = __builtin_bit_cast(unsigned int, f);
    u += 0x7FFFu + ((u >> 16) & 1u);   // round-to-nearest-even
    return (unsigned short)(u >> 16);
}

__device__ __forceinline__ float exp2_fast(float x){
#if __has_builtin(__builtin_amdgcn_exp2f)
    return __builtin_amdgcn_exp2f(x);
#else
    float r; asm("v_exp_f32 %0, %1" : "=v"(r) : "v"(x)); return r;
#endif
}

__device__ __forceinline__ float max3f(float a, float b, float c){
    return fmaxf(fmaxf(a, b), c);      // clang fuses to v_max3_f32
}

__device__ __forceinline__ unsigned cvt_pk_bf16(float a, float b){
    unsigned r;
    asm("v_cvt_pk_bf16_f32 %0, %1, %2" : "=v"(r) : "v"(a), "v"(b));
    return r;
}

__device__ __forceinline__ void gload_lds16(const void* g, void* l){
    __builtin_amdgcn_global_load_lds((const __attribute__((address_space(1))) void*)g,
                                     (__attribute__((address_space(3))) void*)l, 16, 0, 0);
}

// ---------------- GEMM: C[M,512] = (A[M,512] @ W[512,512]^T + bias) * scale ----------------
// MODE 0: f32 row-major C. MODE 1: bf16 row-major C. MODE 2: bf16 V^T write:
//   Vt[(b*8+h)*64 + d][t] <- C[bt][col], b=bt>>12, t=bt&4095, h=col>>6, d=col&63.
template<int MODE>
__device__ __forceinline__ void gemm_body(const float* __restrict__ A, const float* __restrict__ W,
                                          const float* __restrict__ bias, void* __restrict__ Cout,
                                          int m0, int n0, float scale)
{
    constexpr int K = 512, N = 512;
    __shared__ ushort_t As[128*64];
    __shared__ ushort_t Bs[128*64];

    const int tid  = threadIdx.x;
    const int lane = tid & 63;
    const int w    = tid >> 6;
    const int g    = lane >> 4;
    const int c16  = lane & 15;
    const int wm   = w >> 1, wn = w & 1;

    f32x4 acc[4][4];
#pragma unroll
    for (int i=0;i<4;i++)
#pragma unroll
        for (int j=0;j<4;j++) acc[i][j] = (f32x4){0.f,0.f,0.f,0.f};

#pragma unroll 1
    for (int kt=0; kt<K/64; kt++){
        __syncthreads();
#pragma unroll
        for (int j=0;j<4;j++){
            int cid = j*256 + tid;
            int row = cid >> 3, ch = cid & 7;
            const float* srcA = A + (size_t)(m0+row)*K + kt*64 + ch*8;
            const float* srcB = W + (size_t)(n0+row)*K + kt*64 + ch*8;
            float4 a0 = *(const float4*)srcA;
            float4 a1 = *(const float4*)(srcA+4);
            float4 b0 = *(const float4*)srcB;
            float4 b1 = *(const float4*)(srcB+4);
            ushort8 va, vb;
            va[0]=f2b(a0.x); va[1]=f2b(a0.y); va[2]=f2b(a0.z); va[3]=f2b(a0.w);
            va[4]=f2b(a1.x); va[5]=f2b(a1.y); va[6]=f2b(a1.z); va[7]=f2b(a1.w);
            vb[0]=f2b(b0.x); vb[1]=f2b(b0.y); vb[2]=f2b(b0.z); vb[3]=f2b(b0.w);
            vb[4]=f2b(b1.x); vb[5]=f2b(b1.y); vb[6]=f2b(b1.z); vb[7]=f2b(b1.w);
            int dst = row*64 + ((ch ^ (row & 7))<<3);
            *(ushort8*)&As[dst] = va;
            *(ushort8*)&Bs[dst] = vb;
        }
        __syncthreads();
#pragma unroll
        for (int ks=0; ks<2; ks++){
            bf16x8 af[4], bfr[4];
#pragma unroll
            for (int f=0; f<4; f++){
                int rowa = wm*64 + f*16 + c16;
                af[f]  = *(const bf16x8*)&As[rowa*64 + (((ks*4+g) ^ (rowa&7))<<3)];
                int rowb = wn*64 + f*16 + c16;
                bfr[f] = *(const bf16x8*)&Bs[rowb*64 + (((ks*4+g) ^ (rowb&7))<<3)];
            }
#pragma unroll
            for (int fm=0; fm<4; fm++)
#pragma unroll
                for (int fn=0; fn<4; fn++)
                    acc[fm][fn] = MFMA_BF16(af[fm], bfr[fn], acc[fm][fn]);
        }
    }
#pragma unroll
    for (int fm=0; fm<4; fm++)
#pragma unroll
        for (int fn=0; fn<4; fn++){
            int col = n0 + wn*64 + fn*16 + c16;
            float bv = bias[col];
            if (MODE == 2){
                // transposed V^T store: 4 consecutive t at fixed d -> 8B store
                int t0r = m0 + wm*64 + fm*16 + g*4;          // 4-aligned
                int b2  = t0r >> 12;                          // tile never crosses b
                int t   = t0r & 4095;
                int h2  = col >> 6, d = col & 63;
                ushort4_t u;
#pragma unroll
                for (int r=0; r<4; r++) u[r] = f2b(acc[fm][fn][r] + bv);
                ushort_t* dst = (ushort_t*)Cout + ((size_t)(b2*NH_ + h2)*HD_ + d)*T_SEQ + t;
                *(ushort4_t*)dst = u;
            } else {
#pragma unroll
                for (int r=0; r<4; r++){
                    int rowm = m0 + wm*64 + fm*16 + g*4 + r;
                    float vv = (acc[fm][fn][r] + bv) * scale;
                    if (MODE == 1) ((ushort_t*)Cout)[(size_t)rowm*N + col] = f2b(vv);
                    else           ((float*)Cout)[(size_t)rowm*N + col]   = vv;
                }
            }
        }
}

__global__ __launch_bounds__(256,2) void gemm_qkv_kernel(
    const float* __restrict__ q, const float* __restrict__ k, const float* __restrict__ v,
    const float* __restrict__ Wq, const float* __restrict__ bq,
    const float* __restrict__ Wk, const float* __restrict__ bk,
    const float* __restrict__ Wv, const float* __restrict__ bv,
    ushort_t* __restrict__ QKVp)
{
    int z = blockIdx.z;
    const float* A  = (z==0) ? q  : (z==1 ? k  : v);
    const float* W  = (z==0) ? Wq : (z==1 ? Wk : Wv);
    const float* bb = (z==0) ? bq : (z==1 ? bk : bv);
    ushort_t* C = QKVp + (size_t)z * (size_t)(2*T_SEQ) * DM;
    if (z == 2)
        gemm_body<2>(A, W, bb, C, blockIdx.x*128, blockIdx.y*128, 1.0f);   // V^T direct
    else
        gemm_body<1>(A, W, bb, C, blockIdx.x*128, blockIdx.y*128,
                     (z==0) ? QSCALE : 1.0f);                               // bake 0.125*log2e into Q
}

__global__ __launch_bounds__(256,2) void gemm_out_kernel(
    const float* __restrict__ O, const float* __restrict__ Wo,
    const float* __restrict__ bo, float* __restrict__ out)
{
    gemm_body<0>(O, Wo, bo, out, blockIdx.x*128, blockIdx.y*128, 1.0f);
}

// ---------------- Flash attention (r8 pipeline + ones-MFMA lsum) ----------------
// 512 thr (8 waves), 128 q rows/block (wave = 16 rows), KV tile 64, dbuf K/V^T.
// Swapped QK^T: S^T = mfma(K, Q): lane owns q-row c16, kv = n*16+g*4+r.
// One-tile-delayed PV; lsum = ones-MFMA column-sums of the SAME pb that PV uses
// (denominator == sum of numerator weights; cannot diverge from PV).
// NOTE: correctness is schedule-sensitive (unroll-2, ks-outer reorder, fr
// prefetch, and launch_bounds changes each corrupted output in r12-r15).
// Do NOT perturb the K-loop structure without re-validation.
__global__ __launch_bounds__(512,4) void flash_kernel(
    const ushort_t* __restrict__ Qp, const ushort_t* __restrict__ Kp, const ushort_t* __restrict__ Vt,
    const float* __restrict__ frac, const float* __restrict__ alphap, const float* __restrict__ alphan,
    float* __restrict__ O)
{
    // XCD-aware: 2 bh per XCD slot; their K/V (2 MB) live in that XCD's L2
    int i    = blockIdx.x;
    int slot = i & 7;
    int seq  = i >> 3;                   // [0,64)
    int bh   = slot*2 + (seq >> 5);
    int qt   = seq & 31;
    int b    = bh >> 3, h = bh & 7;
    int q0   = qt * 128;

    const int tid  = threadIdx.x;
    const int w    = tid >> 6;           // [0,8)
    const int lane = tid & 63;
    const int g    = lane >> 4;
    const int c16  = lane & 15;

    __shared__ ushort_t Ks [2][64*64];   // [kv][d], chunk ^ (row&7)
    __shared__ ushort_t VTs[2][64*64];   // [d][kv], chunk ^ (row&7)
    __shared__ ushort_t PW [8][16*64];   // per-wave P^T as [q][kv], pair-swizzled

    const ushort_t* Qbase = Qp + (size_t)(b*T_SEQ)*DM + h*HD_;
    const ushort_t* Kbase = Kp + (size_t)(b*T_SEQ)*DM + h*HD_;
    const ushort_t* Vtb   = Vt + (size_t)bh*HD_*T_SEQ;
    const float*    fr    = frac + b*T_SEQ;
    const float c1 = 0.5f*(alphap[h] + alphan[h]) * LOG2E;   // bias = c1*dd + c2*|dd|
    const float c2 = 0.5f*(alphap[h] - alphan[h]) * LOG2E;
    const int qrow = q0 + w*16;

    // Q fragments (B-operand: col = c16, k = ks*32 + g*8 + e)
    bf16x8 qa[2];
#pragma unroll
    for (int ks=0; ks<2; ks++)
        qa[ks] = *(const bf16x8*)(Qbase + (size_t)(qrow + c16)*DM + ks*32 + g*8);
    const float fi = fr[qrow + c16];     // this lane's q-row frac

    // ones vector for the lsum MFMA
    ushort8 ou;
#pragma unroll
    for (int j=0;j<8;j++) ou[j] = 0x3F80;
    const bf16x8 ones = __builtin_bit_cast(bf16x8, ou);

    float m2 = -1e30f;                   // running max (log2 domain)
    f32x4 acc[4];                        // O^T: lane holds q=c16, d = dt*16+g*4+r
    f32x4 asum;                          // row-sum accumulator (all regs equal)
#pragma unroll
    for (int dt=0; dt<4; dt++) acc[dt] = (f32x4){0.f,0.f,0.f,0.f};
    asum = (f32x4){0.f,0.f,0.f,0.f};

    bf16x8 vbp[2][4];                    // V^T frags of tile t, consumed by PV at t+1

#define STAGE(BUF, KV0)                                                          \
    {                                                                            \
        int cb  = w*64;                                                          \
        int idx = cb + lane;                                                     \
        int row = idx >> 3, cc = idx & 7;                                        \
        int cs  = cc ^ (row & 7);                                                \
        gload_lds16(Kbase + (size_t)((KV0)+row)*DM + cs*8, &Ks[BUF][cb*8]);      \
        gload_lds16(Vtb + (size_t)row*T_SEQ + (KV0) + cs*8, &VTs[BUF][cb*8]);    \
    }

    STAGE(0, 0);
    asm volatile("s_waitcnt vmcnt(0)" ::: "memory");
    __syncthreads();

    int buf = 0;
#pragma unroll 1
    for (int kt=0; kt<T_SEQ/64; kt++){
        int kv0 = kt*64;
        if (kt+1 < T_SEQ/64) STAGE(buf^1, kv0+64);

        // --- P(t-1) fragment reads (issue early; consumed by PV cluster) ---
        bf16x8 pb0, pb1;
        if (kt > 0){
            pb0 = *(const bf16x8*)&PW[w][c16*64 + (((    g) ^ (c16&7))<<3)];
            pb1 = *(const bf16x8*)&PW[w][c16*64 + (((4 + g) ^ (c16&7))<<3)];
        }

        // --- S^T = K Q^T (Q pre-scaled by 0.125*log2e) ---
        f32x4 s[4];                      // s[n][r]: kv = n*16+g*4+r, q = c16
#pragma unroll
        for (int n=0; n<4; n++) s[n] = (f32x4){0.f,0.f,0.f,0.f};
        __builtin_amdgcn_s_setprio(1);
#pragma unroll
        for (int n=0; n<4; n++){
#pragma unroll
            for (int ks=0; ks<2; ks++){
                int row = n*16 + c16;
                bf16x8 kb = *(const bf16x8*)&Ks[buf][row*64 + (((ks*4+g) ^ (row&7))<<3)];
                s[n] = MFMA_BF16(kb, qa[ks], s[n]);   // A=K, B=Q
            }
        }
        // --- PV(t-1) + lsum(t-1): all operands in registers ---
        if (kt > 0){
            asum = MFMA_BF16(ones, pb0, asum);
#pragma unroll
            for (int dt=0; dt<4; dt++) acc[dt] = MFMA_BF16(vbp[0][dt], pb0, acc[dt]);
            asum = MFMA_BF16(ones, pb1, asum);
#pragma unroll
            for (int dt=0; dt<4; dt++) acc[dt] = MFMA_BF16(vbp[1][dt], pb1, acc[dt]);
        }
        __builtin_amdgcn_s_setprio(0);
        // pin compile-time order: PW pack-writes below must not move above pb reads
        __builtin_amdgcn_sched_barrier(0);

        // --- bias (log2 domain, select-free algebra) ---
#pragma unroll
        for (int n=0; n<4; n++){
            f32x4 fj = *(const f32x4*)&fr[kv0 + n*16 + g*4];
#pragma unroll
            for (int r=0; r<4; r++){
                float dd = fj[r] - fi;
                s[n][r] = fmaf(c1, dd, fmaf(c2, fabsf(dd), s[n][r]));
            }
        }
        // in-lane max via max3 trees, then cross-lane (4 lanes share a q-row)
        float mx;
        {
            float t0 = max3f(s[0][0], s[0][1], s[0][2]);
            float t1 = max3f(s[0][3], s[1][0], s[1][1]);
            float t2 = max3f(s[1][2], s[1][3], s[2][0]);
            float t3 = max3f(s[2][1], s[2][2], s[2][3]);
            float t4 = max3f(s[3][0], s[3][1], s[3][2]);
            mx = fmaxf(max3f(t0, t1, t2), max3f(t3, t4, s[3][3]));
        }
        mx = fmaxf(mx, __shfl_xor(mx, 16));
        mx = fmaxf(mx, __shfl_xor(mx, 32));

        // --- defer-max rescale (threshold 12 in log2 ~ e^8.3) ---
        // acc/asum already include PV(t-1) -> ordering identical to r7/r8
        if (__any(mx > m2 + 12.0f)){
            float mnew = fmaxf(m2, mx);
            float fac  = exp2_fast(m2 - mnew);
#pragma unroll
            for (int r=0; r<4; r++) asum[r] *= fac;
#pragma unroll
            for (int dt=0; dt<4; dt++)
#pragma unroll
                for (int r=0; r<4; r++) acc[dt][r] *= fac;
            m2 = mnew;
        }

        // --- exp2, pack P -> LDS ---
#pragma unroll
        for (int n=0; n<4; n++){
#pragma unroll
            for (int r=0; r<4; r++) s[n][r] = exp2_fast(s[n][r] - m2);
            unsigned pk0 = cvt_pk_bf16(s[n][0], s[n][1]);
            unsigned pk1 = cvt_pk_bf16(s[n][2], s[n][3]);
            uint2 u; u.x = pk0; u.y = pk1;
            int off = c16*64 + (((n*2 + (g>>1)) ^ (c16 & 7))<<3) + ((g&1)<<2);
            *(uint2*)&PW[w][off] = u;
        }

        // --- V(t) -> regs for next iteration's PV (VTs[buf] stable this iter) ---
#pragma unroll
        for (int ks=0; ks<2; ks++)
#pragma unroll
            for (int dt=0; dt<4; dt++){
                int vr = dt*16 + c16;
                vbp[ks][dt] = *(const bf16x8*)&VTs[buf][vr*64 + (((ks*4+g) ^ (vr&7))<<3)];
            }

        asm volatile("s_waitcnt vmcnt(0)" ::: "memory");
        __syncthreads();
        buf ^= 1;
    }
#undef STAGE

    // --- epilogue PV(T-1): PW visible (final barrier crossed) ---
    {
        bf16x8 pb0 = *(const bf16x8*)&PW[w][c16*64 + (((    g) ^ (c16&7))<<3)];
        bf16x8 pb1 = *(const bf16x8*)&PW[w][c16*64 + (((4 + g) ^ (c16&7))<<3)];
        asum = MFMA_BF16(ones, pb0, asum);
#pragma unroll
        for (int dt=0; dt<4; dt++) acc[dt] = MFMA_BF16(vbp[0][dt], pb0, acc[dt]);
        asum = MFMA_BF16(ones, pb1, asum);
#pragma unroll
        for (int dt=0; dt<4; dt++) acc[dt] = MFMA_BF16(vbp[1][dt], pb1, acc[dt]);
    }

    // --- store: O[b, qrow+c16, h*64 + dt*16 + g*4 + r] ---
    float inv = 1.0f / asum[0];
    float* orow = O + (size_t)(b*T_SEQ + qrow + c16)*DM + h*HD_;
#pragma unroll
    for (int dt=0; dt<4; dt++){
        float4 o4;
        o4.x = acc[dt][0]*inv; o4.y = acc[dt][1]*inv;
        o4.z = acc[dt][2]*inv; o4.w = acc[dt][3]*inv;
        *(float4*)(orow + dt*16 + g*4) = o4;
    }
}

// ---------------- launcher ----------------
extern "C" void kernel_launch(void* const* d_in, const int* in_sizes, int n_in,
                              void* d_out, int out_size, void* d_ws, size_t ws_size,
                              hipStream_t stream)
{
    const float* q  = (const float*)d_in[0];
    const float* k  = (const float*)d_in[1];
    const float* v  = (const float*)d_in[2];
    const float* fr = (const float*)d_in[3];
    const float* Wq = (const float*)d_in[4];
    const float* bq = (const float*)d_in[5];
    const float* Wk = (const float*)d_in[6];
    const float* bk = (const float*)d_in[7];
    const float* Wv = (const float*)d_in[8];
    const float* bv = (const float*)d_in[9];
    const float* Wo = (const float*)d_in[10];
    const float* bo = (const float*)d_in[11];
    const float* ap = (const float*)d_in[12];
    const float* an = (const float*)d_in[13];

    const size_t MT = (size_t)(2*T_SEQ) * DM;              // 4M elements
    ushort_t* QKVp = (ushort_t*)d_ws;                      // Q, K, V^T bf16 (24 MB)
    float*    O    = (float*)((char*)d_ws + 3*MT*sizeof(ushort_t)); // 16 MB f32

    dim3 gq(64, 4, 3);
    gemm_qkv_kernel<<<gq, 256, 0, stream>>>(q,k,v,Wq,bq,Wk,bk,Wv,bv,QKVp);

    flash_kernel<<<512, 512, 0, stream>>>(QKVp, QKVp + MT, QKVp + 2*MT, fr, ap, an, O);

    dim3 go(64, 4, 1);
    gemm_out_kernel<<<go, 256, 0, stream>>>(O, Wo, bo, (float*)d_out);
}